// Round 1
// baseline (33136.887 us; speedup 1.0000x reference)
//
#include <hip/hip_runtime.h>
#include <hip/hip_fp16.h>

typedef unsigned short u16;
typedef unsigned int   u32;

#define B_   32
#define T_   2048
#define C_   256
#define H_   256
#define TC_  1024
#define M_   (B_*TC_)   // 32768

using bf16x8 = __attribute__((ext_vector_type(8))) short;
using f32x4  = __attribute__((ext_vector_type(4))) float;

__device__ __forceinline__ u16 f2bf(float f) {
  u32 u = __float_as_uint(f);
  u32 r = u + 0x7fffu + ((u >> 16) & 1u);
  return (u16)(r >> 16);
}
__device__ __forceinline__ float sigmf(float x) { return 1.f / (1.f + __expf(-x)); }

// ---------------- casts ----------------
__global__ void cast_bf16_kernel(const float* __restrict__ src, u16* __restrict__ dst, int n) {
  int i = blockIdx.x * 256 + threadIdx.x;
  if (i < n) dst[i] = f2bf(src[i]);
}
__global__ void cast_f16_kernel(const float* __restrict__ src, u16* __restrict__ dst, int n) {
  int i = blockIdx.x * 256 + threadIdx.x;
  if (i < n) dst[i] = __half_as_ushort(__float2half(src[i]));
}

// ---------------- conv + bn + relu -> y bf16 (B*TC, C) ----------------
__global__ __launch_bounds__(256)
void conv_bn_kernel(const float* __restrict__ x, const float* __restrict__ cw,
                    const float* __restrict__ cb, const float* __restrict__ bng,
                    const float* __restrict__ bnb, const float* __restrict__ bnm,
                    const float* __restrict__ bnv, u16* __restrict__ ybf) {
  int c = threadIdx.x;
  int bt = blockIdx.x;                  // b*TC + t
  int t = bt & (TC_ - 1), b = bt >> 10;
  const float* xr = x + (size_t)b * T_;
  float xm1 = (t > 0) ? xr[2 * t - 1] : 0.f;
  float x0 = xr[2 * t], xp1 = xr[2 * t + 1];
  float w0 = cw[c * 3], w1 = cw[c * 3 + 1], w2 = cw[c * 3 + 2];
  float inv = bng[c] * rsqrtf(bnv[c] + 1e-5f);
  float beta = bnb[c] - bnm[c] * inv;
  float v = w0 * xm1 + w1 * x0 + w2 * xp1 + cb[c];
  v = v * inv + beta;
  v = fmaxf(v, 0.f);
  ybf[(size_t)bt * C_ + c] = f2bf(v);
}

// ---------------- projection GEMM: pre = A(bf16 MxK) @ W(bf16 1024xK)^T + bias ----------------
// MFMA 16x16x32 bf16. A frag: m=lane&15, k=quad*8+j (contiguous row bytes).
// B frag: n=lane&15, k=quad*8+j -> load W rows directly. D: col=lane&15, row=quad*4+reg.
__global__ __launch_bounds__(256)
void proj_gemm_kernel(const u16* __restrict__ A,
                      const u16* __restrict__ Wf, const u16* __restrict__ Wr,
                      const float* __restrict__ bf, const float* __restrict__ br,
                      float* __restrict__ outf, float* __restrict__ outr,
                      int K) {
  const u16* W = blockIdx.z ? Wr : Wf;
  const float* bias = blockIdx.z ? br : bf;
  float* out = blockIdx.z ? outr : outf;
  int wave = threadIdx.x >> 6, lane = threadIdx.x & 63;
  int l16 = lane & 15, quad = lane >> 4;
  int m0 = blockIdx.x * 64 + (wave >> 1) * 32;
  int n0 = blockIdx.y * 64 + (wave & 1) * 32;
  const u16* a0p = A + (size_t)(m0 + l16) * K + quad * 8;
  const u16* a1p = a0p + (size_t)16 * K;
  const u16* b0p = W + (size_t)(n0 + l16) * K + quad * 8;
  const u16* b1p = b0p + (size_t)16 * K;
  f32x4 acc00 = {0.f, 0.f, 0.f, 0.f}, acc01 = acc00, acc10 = acc00, acc11 = acc00;
  for (int k = 0; k < K; k += 32) {
    bf16x8 a0 = *(const bf16x8*)(a0p + k);
    bf16x8 a1 = *(const bf16x8*)(a1p + k);
    bf16x8 b0 = *(const bf16x8*)(b0p + k);
    bf16x8 b1 = *(const bf16x8*)(b1p + k);
    acc00 = __builtin_amdgcn_mfma_f32_16x16x32_bf16(a0, b0, acc00, 0, 0, 0);
    acc01 = __builtin_amdgcn_mfma_f32_16x16x32_bf16(a0, b1, acc01, 0, 0, 0);
    acc10 = __builtin_amdgcn_mfma_f32_16x16x32_bf16(a1, b0, acc10, 0, 0, 0);
    acc11 = __builtin_amdgcn_mfma_f32_16x16x32_bf16(a1, b1, acc11, 0, 0, 0);
  }
  float bv0 = bias[n0 + l16];
  float bv1 = bias[n0 + 16 + l16];
  int r0 = m0 + quad * 4;
#pragma unroll
  for (int r = 0; r < 4; ++r) {
    out[(size_t)(r0 + r) * 1024 + n0 + l16]           = acc00[r] + bv0;
    out[(size_t)(r0 + r) * 1024 + n0 + 16 + l16]      = acc01[r] + bv1;
    out[(size_t)(r0 + 16 + r) * 1024 + n0 + l16]      = acc10[r] + bv0;
    out[(size_t)(r0 + 16 + r) * 1024 + n0 + 16 + l16] = acc11[r] + bv1;
  }
}

// ---------------- LSTM scan: 256 WGs = 64 chains x 4 gate-slices ----------------
// chain = (b, dir); slice q owns gate rows [256q, 256q+256). f16 w_hh slice in LDS.
// Per step: partial dots -> publish gates to device-coherent gbuf -> 4-WG barrier
// (monotonic counter) -> every WG redundantly computes c,h (identical fp ops).
__global__ __launch_bounds__(512, 1)
void scan_kernel(const float* __restrict__ pre_f, const float* __restrict__ pre_r,
                 const u16* __restrict__ whh_f, const u16* __restrict__ whh_r,
                 void* __restrict__ outp, int out_bf16,
                 int* __restrict__ cnt, float* __restrict__ gbuf) {
  extern __shared__ char smem[];
  u32* whh2   = (u32*)smem;                    // [256][129] padded f16-pairs (132096 B)
  float* hbuf = (float*)(smem + 132096);       // [256]
  float* cbuf = hbuf + 256;                    // [256]
  float* pred = cbuf + 256;                    // [2][256]
  float* gtmp = pred + 512;                    // [1024]
  const int tid = threadIdx.x;
  const int bid = blockIdx.x;
  const int chain = bid >> 2, q = bid & 3;
  const int dir = chain & 1, b = chain >> 1;
  const float* pre = dir ? pre_r : pre_f;
  const u32* wsrc = (const u32*)(dir ? whh_r : whh_f) + (size_t)q * 256 * 128;
  for (int idx = tid; idx < 256 * 128; idx += 512) {
    int g = idx >> 7, j = idx & 127;
    whh2[g * 129 + j] = wsrc[idx];
  }
  if (tid < 256) { hbuf[tid] = 0.f; cbuf[tid] = 0.f; }
  __syncthreads();
  const int gl = tid & 255, half = tid >> 8;
  const u32* wrow = whh2 + gl * 129 + half * 64;
  const float* hb = hbuf + half * 128;
  int* mycnt = cnt + chain;
  float* gs0 = gbuf + (size_t)chain * 2048;
  float* gs1 = gs0 + 1024;
  for (int t = 0; t < TC_; ++t) {
    int tt = dir ? (TC_ - 1 - t) : t;
    float pre_v = (half == 0) ? pre[((size_t)b * TC_ + tt) * 1024 + q * 256 + gl] : 0.f;
    float acc0 = 0.f, acc1 = 0.f, acc2 = 0.f, acc3 = 0.f;
#pragma unroll
    for (int j = 0; j < 64; j += 2) {
      u32 u0 = wrow[j], u1 = wrow[j + 1];
      float4 hv = *(const float4*)(hb + 2 * j);
      float2 f0 = __half22float2(*(const __half2*)&u0);
      float2 f1 = __half22float2(*(const __half2*)&u1);
      acc0 = fmaf(f0.x, hv.x, acc0);
      acc1 = fmaf(f0.y, hv.y, acc1);
      acc2 = fmaf(f1.x, hv.z, acc2);
      acc3 = fmaf(f1.y, hv.w, acc3);
    }
    pred[half * 256 + gl] = (acc0 + acc1) + (acc2 + acc3);
    __syncthreads();
    float* gsl = (t & 1) ? gs1 : gs0;
    if (half == 0) {
      float dot = pred[gl] + pred[256 + gl] + pre_v;
      __hip_atomic_store(gsl + q * 256 + gl, dot, __ATOMIC_RELAXED, __HIP_MEMORY_SCOPE_AGENT);
    }
    __syncthreads();
    if (tid == 0) {
      __threadfence();                 // order gate stores before counter bump
      atomicAdd(mycnt, 1);
      int target = 4 * (t + 1);
      while (__hip_atomic_load(mycnt, __ATOMIC_RELAXED, __HIP_MEMORY_SCOPE_AGENT) < target) {}
      (void)__hip_atomic_load(mycnt, __ATOMIC_ACQUIRE, __HIP_MEMORY_SCOPE_AGENT);
    }
    __syncthreads();
    for (int idx = tid; idx < 1024; idx += 512)
      gtmp[idx] = __hip_atomic_load(gsl + idx, __ATOMIC_RELAXED, __HIP_MEMORY_SCOPE_AGENT);
    __syncthreads();
    if (half == 0) {
      float gi = gtmp[gl], gf = gtmp[256 + gl], gg = gtmp[512 + gl], go = gtmp[768 + gl];
      float c = sigmf(gf) * cbuf[gl] + sigmf(gi) * tanhf(gg);
      float h = sigmf(go) * tanhf(c);
      cbuf[gl] = c;
      hbuf[gl] = h;
      if (q == 0) {
        size_t oi = ((size_t)b * TC_ + tt) * 512 + dir * 256 + gl;
        if (out_bf16) ((u16*)outp)[oi] = f2bf(h);
        else          ((float*)outp)[oi] = h;
      }
    }
    __syncthreads();
  }
}

// ---------------- FC heads ----------------
__global__ void fc_init_kernel(const float* __restrict__ fc1_b, const float* __restrict__ fc2_b,
                               float* __restrict__ out) {
  int i = blockIdx.x * 256 + threadIdx.x;
  if (i < 3200) out[i] = fc1_b[i % 100];
  else if (i < 6080) out[i] = fc2_b[(i - 3200) % 90];
}

#define FCK 2048
#define FCSUB 64
__global__ __launch_bounds__(256)
void fc_kernel(const float* __restrict__ flat, const float* __restrict__ w1,
               const float* __restrict__ w2, float* __restrict__ out) {
  __shared__ float fs[32][FCSUB + 1];
  __shared__ float ws[192][FCSUB + 1];
  int tid = threadIdx.x;
  int tn = tid & 31, tb = tid >> 5;
  size_t k0 = (size_t)blockIdx.x * FCK;
  float acc[4][6] = {};
  for (int kc = 0; kc < FCK; kc += FCSUB) {
    __syncthreads();
    for (int idx = tid; idx < 32 * FCSUB; idx += 256) {
      int bb = idx >> 6, j = idx & 63;
      fs[bb][j] = flat[(size_t)bb * 524288 + k0 + kc + j];
    }
    for (int idx = tid; idx < 192 * FCSUB; idx += 256) {
      int n = idx >> 6, j = idx & 63;
      float v = 0.f;
      if (n < 100)      v = w1[(size_t)n * 524288 + k0 + kc + j];
      else if (n < 190) v = w2[(size_t)(n - 100) * 524288 + k0 + kc + j];
      ws[n][j] = v;
    }
    __syncthreads();
    for (int j = 0; j < FCSUB; ++j) {
      float fv[4], wv[6];
#pragma unroll
      for (int m = 0; m < 4; ++m) fv[m] = fs[tb + 8 * m][j];
#pragma unroll
      for (int mm = 0; mm < 6; ++mm) wv[mm] = ws[tn + 32 * mm][j];
#pragma unroll
      for (int m = 0; m < 4; ++m)
#pragma unroll
        for (int mm = 0; mm < 6; ++mm) acc[m][mm] = fmaf(fv[m], wv[mm], acc[m][mm]);
    }
  }
#pragma unroll
  for (int m = 0; m < 4; ++m)
#pragma unroll
    for (int mm = 0; mm < 6; ++mm) {
      int n = tn + 32 * mm, bb = tb + 8 * m;
      if (n < 190) {
        int oi = (n < 100) ? (bb * 100 + n) : (3200 + bb * 90 + (n - 100));
        atomicAdd(out + oi, acc[m][mm]);
      }
    }
}

// ---------------- launcher ----------------
extern "C" void kernel_launch(void* const* d_in, const int* in_sizes, int n_in,
                              void* d_out, int out_size, void* d_ws, size_t ws_size,
                              hipStream_t stream) {
  const float* x       = (const float*)d_in[0];
  const float* conv_w  = (const float*)d_in[1];
  const float* conv_b  = (const float*)d_in[2];
  const float* bn_g    = (const float*)d_in[3];
  const float* bn_bb   = (const float*)d_in[4];
  const float* bn_m    = (const float*)d_in[5];
  const float* bn_v    = (const float*)d_in[6];
  const float* w_ih_f0 = (const float*)d_in[7];
  const float* w_hh_f0 = (const float*)d_in[8];
  const float* b_f0    = (const float*)d_in[9];
  const float* w_ih_r0 = (const float*)d_in[10];
  const float* w_hh_r0 = (const float*)d_in[11];
  const float* b_r0    = (const float*)d_in[12];
  const float* w_ih_f1 = (const float*)d_in[13];
  const float* w_hh_f1 = (const float*)d_in[14];
  const float* b_f1    = (const float*)d_in[15];
  const float* w_ih_r1 = (const float*)d_in[16];
  const float* w_hh_r1 = (const float*)d_in[17];
  const float* b_r1    = (const float*)d_in[18];
  const float* fc1_w   = (const float*)d_in[19];
  const float* fc1_b   = (const float*)d_in[20];
  const float* fc2_w   = (const float*)d_in[21];
  const float* fc2_b   = (const float*)d_in[22];
  float* out = (float*)d_out;

  char* base = (char*)d_ws;
  size_t off = 0;
  auto carve = [&](size_t bytes) -> char* {
    char* p = base + off;
    off += (bytes + 511) & ~(size_t)511;
    return p;
  };
  int*   cnt0  = (int*)carve(256);
  int*   cnt1  = (int*)carve(256);
  float* gbuf  = (float*)carve((size_t)64 * 2048 * 4);
  u16*   ybf   = (u16*)carve((size_t)M_ * 256 * 2);
  u16*   wb_f0 = (u16*)carve((size_t)262144 * 2);
  u16*   wb_r0 = (u16*)carve((size_t)262144 * 2);
  u16*   wb_f1 = (u16*)carve((size_t)524288 * 2);
  u16*   wb_r1 = (u16*)carve((size_t)524288 * 2);
  u16*   wh_f0 = (u16*)carve((size_t)262144 * 2);
  u16*   wh_r0 = (u16*)carve((size_t)262144 * 2);
  u16*   wh_f1 = (u16*)carve((size_t)262144 * 2);
  u16*   wh_r1 = (u16*)carve((size_t)262144 * 2);
  u16*   h0cat = (u16*)carve((size_t)M_ * 512 * 2);
  float* h1cat = (float*)carve((size_t)M_ * 512 * 4);
  float* pre_f = (float*)carve((size_t)M_ * 1024 * 4);
  float* pre_r = (float*)carve((size_t)M_ * 1024 * 4);
  if (off > ws_size) return;   // workspace too small: bail cleanly

  hipMemsetAsync(d_ws, 0, 1024, stream);   // zero both counter arrays
  hipFuncSetAttribute((const void*)scan_kernel,
                      hipFuncAttributeMaxDynamicSharedMemorySize, 140288);

  cast_bf16_kernel<<<1024, 256, 0, stream>>>(w_ih_f0, wb_f0, 262144);
  cast_bf16_kernel<<<1024, 256, 0, stream>>>(w_ih_r0, wb_r0, 262144);
  cast_bf16_kernel<<<2048, 256, 0, stream>>>(w_ih_f1, wb_f1, 524288);
  cast_bf16_kernel<<<2048, 256, 0, stream>>>(w_ih_r1, wb_r1, 524288);
  cast_f16_kernel<<<1024, 256, 0, stream>>>(w_hh_f0, wh_f0, 262144);
  cast_f16_kernel<<<1024, 256, 0, stream>>>(w_hh_r0, wh_r0, 262144);
  cast_f16_kernel<<<1024, 256, 0, stream>>>(w_hh_f1, wh_f1, 262144);
  cast_f16_kernel<<<1024, 256, 0, stream>>>(w_hh_r1, wh_r1, 262144);

  conv_bn_kernel<<<M_, 256, 0, stream>>>(x, conv_w, conv_b, bn_g, bn_bb, bn_m, bn_v, ybf);

  proj_gemm_kernel<<<dim3(512, 16, 2), 256, 0, stream>>>(
      ybf, wb_f0, wb_r0, b_f0, b_r0, pre_f, pre_r, 256);

  {
    const float* a0 = pre_f; const float* a1 = pre_r;
    const u16* w0 = wh_f0;  const u16* w1 = wh_r0;
    void* op = (void*)h0cat; int obf = 1;
    int* cp = cnt0; float* gp = gbuf;
    void* args[] = { &a0, &a1, &w0, &w1, &op, &obf, &cp, &gp };
    hipLaunchCooperativeKernel((const void*)scan_kernel, dim3(256), dim3(512),
                               args, 140288, stream);
  }

  proj_gemm_kernel<<<dim3(512, 16, 2), 256, 0, stream>>>(
      h0cat, wb_f1, wb_r1, b_f1, b_r1, pre_f, pre_r, 512);

  {
    const float* a0 = pre_f; const float* a1 = pre_r;
    const u16* w0 = wh_f1;  const u16* w1 = wh_r1;
    void* op = (void*)h1cat; int obf = 0;
    int* cp = cnt1; float* gp = gbuf;
    void* args[] = { &a0, &a1, &w0, &w1, &op, &obf, &cp, &gp };
    hipLaunchCooperativeKernel((const void*)scan_kernel, dim3(256), dim3(512),
                               args, 140288, stream);
  }

  fc_init_kernel<<<24, 256, 0, stream>>>(fc1_b, fc2_b, out);
  fc_kernel<<<256, 256, 0, stream>>>(h1cat, fc1_w, fc2_w, out);
}

// Round 2
// 5522.826 us; speedup vs baseline: 6.0000x; 6.0000x over previous
//
#include <hip/hip_runtime.h>
#include <hip/hip_fp16.h>

typedef unsigned short u16;
typedef unsigned int   u32;

#define B_   32
#define T_   2048
#define C_   256
#define H_   256
#define TC_  1024
#define M_   (B_*TC_)   // 32768

using bf16x8 = __attribute__((ext_vector_type(8))) short;
using f32x4  = __attribute__((ext_vector_type(4))) float;
typedef _Float16 f16x2 __attribute__((ext_vector_type(2)));

__device__ __forceinline__ u16 f2bf(float f) {
  u32 u = __float_as_uint(f);
  u32 r = u + 0x7fffu + ((u >> 16) & 1u);
  return (u16)(r >> 16);
}
__device__ __forceinline__ float sigmf(float x) { return 1.f / (1.f + __expf(-x)); }
__device__ __forceinline__ float dot2(u32 w, u32 h, float acc) {
  return __builtin_amdgcn_fdot2(__builtin_bit_cast(f16x2, w),
                                __builtin_bit_cast(f16x2, h), acc, false);
}

// ---------------- casts ----------------
__global__ void cast_bf16_kernel(const float* __restrict__ src, u16* __restrict__ dst, int n) {
  int i = blockIdx.x * 256 + threadIdx.x;
  if (i < n) dst[i] = f2bf(src[i]);
}
__global__ void cast_f16_kernel(const float* __restrict__ src, u16* __restrict__ dst, int n) {
  int i = blockIdx.x * 256 + threadIdx.x;
  if (i < n) dst[i] = __half_as_ushort(__float2half(src[i]));
}

// ---------------- conv + bn + relu -> y bf16 (B*TC, C) ----------------
__global__ __launch_bounds__(256)
void conv_bn_kernel(const float* __restrict__ x, const float* __restrict__ cw,
                    const float* __restrict__ cb, const float* __restrict__ bng,
                    const float* __restrict__ bnb, const float* __restrict__ bnm,
                    const float* __restrict__ bnv, u16* __restrict__ ybf) {
  int c = threadIdx.x;
  int bt = blockIdx.x;                  // b*TC + t
  int t = bt & (TC_ - 1), b = bt >> 10;
  const float* xr = x + (size_t)b * T_;
  float xm1 = (t > 0) ? xr[2 * t - 1] : 0.f;
  float x0 = xr[2 * t], xp1 = xr[2 * t + 1];
  float w0 = cw[c * 3], w1 = cw[c * 3 + 1], w2 = cw[c * 3 + 2];
  float inv = bng[c] * rsqrtf(bnv[c] + 1e-5f);
  float beta = bnb[c] - bnm[c] * inv;
  float v = w0 * xm1 + w1 * x0 + w2 * xp1 + cb[c];
  v = v * inv + beta;
  v = fmaxf(v, 0.f);
  ybf[(size_t)bt * C_ + c] = f2bf(v);
}

// ---------------- projection GEMM: pre = A(bf16 MxK) @ W(bf16 1024xK)^T + bias ----------------
__global__ __launch_bounds__(256)
void proj_gemm_kernel(const u16* __restrict__ A,
                      const u16* __restrict__ Wf, const u16* __restrict__ Wr,
                      const float* __restrict__ bf, const float* __restrict__ br,
                      float* __restrict__ outf, float* __restrict__ outr,
                      int K) {
  const u16* W = blockIdx.z ? Wr : Wf;
  const float* bias = blockIdx.z ? br : bf;
  float* out = blockIdx.z ? outr : outf;
  int wave = threadIdx.x >> 6, lane = threadIdx.x & 63;
  int l16 = lane & 15, quad = lane >> 4;
  int m0 = blockIdx.x * 64 + (wave >> 1) * 32;
  int n0 = blockIdx.y * 64 + (wave & 1) * 32;
  const u16* a0p = A + (size_t)(m0 + l16) * K + quad * 8;
  const u16* a1p = a0p + (size_t)16 * K;
  const u16* b0p = W + (size_t)(n0 + l16) * K + quad * 8;
  const u16* b1p = b0p + (size_t)16 * K;
  f32x4 acc00 = {0.f, 0.f, 0.f, 0.f}, acc01 = acc00, acc10 = acc00, acc11 = acc00;
  for (int k = 0; k < K; k += 32) {
    bf16x8 a0 = *(const bf16x8*)(a0p + k);
    bf16x8 a1 = *(const bf16x8*)(a1p + k);
    bf16x8 b0 = *(const bf16x8*)(b0p + k);
    bf16x8 b1 = *(const bf16x8*)(b1p + k);
    acc00 = __builtin_amdgcn_mfma_f32_16x16x32_bf16(a0, b0, acc00, 0, 0, 0);
    acc01 = __builtin_amdgcn_mfma_f32_16x16x32_bf16(a0, b1, acc01, 0, 0, 0);
    acc10 = __builtin_amdgcn_mfma_f32_16x16x32_bf16(a1, b0, acc10, 0, 0, 0);
    acc11 = __builtin_amdgcn_mfma_f32_16x16x32_bf16(a1, b1, acc11, 0, 0, 0);
  }
  float bv0 = bias[n0 + l16];
  float bv1 = bias[n0 + 16 + l16];
  int r0 = m0 + quad * 4;
#pragma unroll
  for (int r = 0; r < 4; ++r) {
    out[(size_t)(r0 + r) * 1024 + n0 + l16]           = acc00[r] + bv0;
    out[(size_t)(r0 + r) * 1024 + n0 + 16 + l16]      = acc01[r] + bv1;
    out[(size_t)(r0 + 16 + r) * 1024 + n0 + l16]      = acc10[r] + bv0;
    out[(size_t)(r0 + 16 + r) * 1024 + n0 + 16 + l16] = acc11[r] + bv1;
  }
}

// ---------------- LSTM scan v2: ONE workgroup per chain, no inter-WG comm ----------------
// 1024 threads. tid = p + 512*kh: thread owns gate rows {p, p+512}, k-half kh
// (k in [128kh, 128kh+128)). Weights per thread: 128 half2 = 96 in VGPRs + 32 in
// LDS (128 KB). h kept as packed f16 pairs in LDS (512 B, broadcast b128 reads).
// Gate partials via 8 KB LDS buffer; c-state in registers of threads 0..255.
// Two __syncthreads per step; zero global-memory synchronization.
#define SCAN_LDS (131072 + 512 + 8192)   // wlds + hbuf + gpart = 139776 B
__global__ __launch_bounds__(1024, 1)
void scan2_kernel(const float* __restrict__ pre_f, const float* __restrict__ pre_r,
                  const u32* __restrict__ whh_f, const u32* __restrict__ whh_r,
                  void* __restrict__ outp, int out_bf16) {
  extern __shared__ char smem[];
  u32*   wlds  = (u32*)smem;                       // [8][1024][4] u32
  u32*   hbuf  = (u32*)(smem + 131072);            // [128] packed f16 pairs
  float* gpart = (float*)(smem + 131072 + 512);    // [2][1024]
  const int tid = threadIdx.x;
  const int p = tid & 511, kh = tid >> 9;
  const int chain = blockIdx.x;
  const int dir = chain & 1, b = chain >> 1;
  const float* pre = dir ? pre_r : pre_f;
  const u32* whh = dir ? whh_r : whh_f;            // f16-pair packed [1024][128]

  // ---- stage weights: rows {p, p+512}, k-half kh -> 96 regs + 8 LDS b128 chunks
  u32 wreg0[48], wreg1[48];
  {
    const u32* w0p = whh + (size_t)p * 128 + kh * 64;
    const u32* w1p = w0p + (size_t)512 * 128;
#pragma unroll
    for (int c = 0; c < 12; ++c) {
      uint4 a = *(const uint4*)(w0p + c * 4);
      wreg0[c*4+0] = a.x; wreg0[c*4+1] = a.y; wreg0[c*4+2] = a.z; wreg0[c*4+3] = a.w;
      uint4 bq = *(const uint4*)(w1p + c * 4);
      wreg1[c*4+0] = bq.x; wreg1[c*4+1] = bq.y; wreg1[c*4+2] = bq.z; wreg1[c*4+3] = bq.w;
    }
#pragma unroll
    for (int c = 0; c < 4; ++c) {
      *(uint4*)(wlds + ((size_t)c * 1024 + tid) * 4)       = *(const uint4*)(w0p + (12 + c) * 4);
      *(uint4*)(wlds + ((size_t)(4 + c) * 1024 + tid) * 4) = *(const uint4*)(w1p + (12 + c) * 4);
    }
  }
  if (tid < 128) hbuf[tid] = 0u;
  float cst = 0.f;
  __syncthreads();

  const u32* hb = hbuf + kh * 64;
  for (int t = 0; t < TC_; ++t) {
    const int tt = dir ? (TC_ - 1 - t) : t;
    float pre0 = 0.f, pre1 = 0.f;
    if (kh == 0) {
      const float* pr = pre + ((size_t)b * TC_ + tt) * 1024;
      pre0 = pr[p]; pre1 = pr[p + 512];
    }
    float acc0 = 0.f, acc1 = 0.f;
#pragma unroll
    for (int c = 0; c < 12; ++c) {
      uint4 h4 = *(const uint4*)(hb + c * 4);
      acc0 = dot2(wreg0[c*4+0], h4.x, acc0);
      acc0 = dot2(wreg0[c*4+1], h4.y, acc0);
      acc0 = dot2(wreg0[c*4+2], h4.z, acc0);
      acc0 = dot2(wreg0[c*4+3], h4.w, acc0);
      acc1 = dot2(wreg1[c*4+0], h4.x, acc1);
      acc1 = dot2(wreg1[c*4+1], h4.y, acc1);
      acc1 = dot2(wreg1[c*4+2], h4.z, acc1);
      acc1 = dot2(wreg1[c*4+3], h4.w, acc1);
    }
#pragma unroll
    for (int c = 0; c < 4; ++c) {
      uint4 h4 = *(const uint4*)(hb + (12 + c) * 4);
      uint4 w0 = *(const uint4*)(wlds + ((size_t)c * 1024 + tid) * 4);
      uint4 w1 = *(const uint4*)(wlds + ((size_t)(4 + c) * 1024 + tid) * 4);
      acc0 = dot2(w0.x, h4.x, acc0);
      acc0 = dot2(w0.y, h4.y, acc0);
      acc0 = dot2(w0.z, h4.z, acc0);
      acc0 = dot2(w0.w, h4.w, acc0);
      acc1 = dot2(w1.x, h4.x, acc1);
      acc1 = dot2(w1.y, h4.y, acc1);
      acc1 = dot2(w1.z, h4.z, acc1);
      acc1 = dot2(w1.w, h4.w, acc1);
    }
    if (kh == 0) { acc0 += pre0; acc1 += pre1; }
    gpart[kh * 1024 + p]       = acc0;
    gpart[kh * 1024 + p + 512] = acc1;
    __syncthreads();
    if (tid < 256) {
      const int j = tid;
      float gi = gpart[j]       + gpart[1024 + j];
      float gf = gpart[j + 256] + gpart[1024 + j + 256];
      float gg = gpart[j + 512] + gpart[1024 + j + 512];
      float go = gpart[j + 768] + gpart[1024 + j + 768];
      cst = sigmf(gf) * cst + sigmf(gi) * tanhf(gg);
      float h = sigmf(go) * tanhf(cst);
      size_t oi = ((size_t)b * TC_ + tt) * 512 + (size_t)dir * 256 + j;
      if (out_bf16) ((u16*)outp)[oi] = f2bf(h);
      else          ((float*)outp)[oi] = h;
      u16 hu = __half_as_ushort(__float2half(h));
      u16 hn = (u16)__shfl_down((int)hu, 1);
      if ((j & 1) == 0) hbuf[j >> 1] = (u32)hu | ((u32)hn << 16);
    }
    __syncthreads();
  }
}

// ---------------- FC heads ----------------
__global__ void fc_init_kernel(const float* __restrict__ fc1_b, const float* __restrict__ fc2_b,
                               float* __restrict__ out) {
  int i = blockIdx.x * 256 + threadIdx.x;
  if (i < 3200) out[i] = fc1_b[i % 100];
  else if (i < 6080) out[i] = fc2_b[(i - 3200) % 90];
}

#define FCK 2048
#define FCSUB 64
__global__ __launch_bounds__(256)
void fc_kernel(const float* __restrict__ flat, const float* __restrict__ w1,
               const float* __restrict__ w2, float* __restrict__ out) {
  __shared__ float fs[32][FCSUB + 1];
  __shared__ float ws[192][FCSUB + 1];
  int tid = threadIdx.x;
  int tn = tid & 31, tb = tid >> 5;
  size_t k0 = (size_t)blockIdx.x * FCK;
  float acc[4][6] = {};
  for (int kc = 0; kc < FCK; kc += FCSUB) {
    __syncthreads();
    for (int idx = tid; idx < 32 * FCSUB; idx += 256) {
      int bb = idx >> 6, j = idx & 63;
      fs[bb][j] = flat[(size_t)bb * 524288 + k0 + kc + j];
    }
    for (int idx = tid; idx < 192 * FCSUB; idx += 256) {
      int n = idx >> 6, j = idx & 63;
      float v = 0.f;
      if (n < 100)      v = w1[(size_t)n * 524288 + k0 + kc + j];
      else if (n < 190) v = w2[(size_t)(n - 100) * 524288 + k0 + kc + j];
      ws[n][j] = v;
    }
    __syncthreads();
    for (int j = 0; j < FCSUB; ++j) {
      float fv[4], wv[6];
#pragma unroll
      for (int m = 0; m < 4; ++m) fv[m] = fs[tb + 8 * m][j];
#pragma unroll
      for (int mm = 0; mm < 6; ++mm) wv[mm] = ws[tn + 32 * mm][j];
#pragma unroll
      for (int m = 0; m < 4; ++m)
#pragma unroll
        for (int mm = 0; mm < 6; ++mm) acc[m][mm] = fmaf(fv[m], wv[mm], acc[m][mm]);
    }
  }
#pragma unroll
  for (int m = 0; m < 4; ++m)
#pragma unroll
    for (int mm = 0; mm < 6; ++mm) {
      int n = tn + 32 * mm, bb = tb + 8 * m;
      if (n < 190) {
        int oi = (n < 100) ? (bb * 100 + n) : (3200 + bb * 90 + (n - 100));
        atomicAdd(out + oi, acc[m][mm]);
      }
    }
}

// ---------------- launcher ----------------
extern "C" void kernel_launch(void* const* d_in, const int* in_sizes, int n_in,
                              void* d_out, int out_size, void* d_ws, size_t ws_size,
                              hipStream_t stream) {
  const float* x       = (const float*)d_in[0];
  const float* conv_w  = (const float*)d_in[1];
  const float* conv_b  = (const float*)d_in[2];
  const float* bn_g    = (const float*)d_in[3];
  const float* bn_bb   = (const float*)d_in[4];
  const float* bn_m    = (const float*)d_in[5];
  const float* bn_v    = (const float*)d_in[6];
  const float* w_ih_f0 = (const float*)d_in[7];
  const float* w_hh_f0 = (const float*)d_in[8];
  const float* b_f0    = (const float*)d_in[9];
  const float* w_ih_r0 = (const float*)d_in[10];
  const float* w_hh_r0 = (const float*)d_in[11];
  const float* b_r0    = (const float*)d_in[12];
  const float* w_ih_f1 = (const float*)d_in[13];
  const float* w_hh_f1 = (const float*)d_in[14];
  const float* b_f1    = (const float*)d_in[15];
  const float* w_ih_r1 = (const float*)d_in[16];
  const float* w_hh_r1 = (const float*)d_in[17];
  const float* b_r1    = (const float*)d_in[18];
  const float* fc1_w   = (const float*)d_in[19];
  const float* fc1_b   = (const float*)d_in[20];
  const float* fc2_w   = (const float*)d_in[21];
  const float* fc2_b   = (const float*)d_in[22];
  float* out = (float*)d_out;

  char* base = (char*)d_ws;
  size_t off = 0;
  auto carve = [&](size_t bytes) -> char* {
    char* p = base + off;
    off += (bytes + 511) & ~(size_t)511;
    return p;
  };
  u16*   ybf   = (u16*)carve((size_t)M_ * 256 * 2);
  u16*   wb_f0 = (u16*)carve((size_t)262144 * 2);
  u16*   wb_r0 = (u16*)carve((size_t)262144 * 2);
  u16*   wb_f1 = (u16*)carve((size_t)524288 * 2);
  u16*   wb_r1 = (u16*)carve((size_t)524288 * 2);
  u16*   wh_f0 = (u16*)carve((size_t)262144 * 2);
  u16*   wh_r0 = (u16*)carve((size_t)262144 * 2);
  u16*   wh_f1 = (u16*)carve((size_t)262144 * 2);
  u16*   wh_r1 = (u16*)carve((size_t)262144 * 2);
  u16*   h0cat = (u16*)carve((size_t)M_ * 512 * 2);
  float* h1cat = (float*)carve((size_t)M_ * 512 * 4);
  float* pre_f = (float*)carve((size_t)M_ * 1024 * 4);
  float* pre_r = (float*)carve((size_t)M_ * 1024 * 4);
  if (off > ws_size) return;

  hipFuncSetAttribute((const void*)scan2_kernel,
                      hipFuncAttributeMaxDynamicSharedMemorySize, SCAN_LDS);

  cast_bf16_kernel<<<1024, 256, 0, stream>>>(w_ih_f0, wb_f0, 262144);
  cast_bf16_kernel<<<1024, 256, 0, stream>>>(w_ih_r0, wb_r0, 262144);
  cast_bf16_kernel<<<2048, 256, 0, stream>>>(w_ih_f1, wb_f1, 524288);
  cast_bf16_kernel<<<2048, 256, 0, stream>>>(w_ih_r1, wb_r1, 524288);
  cast_f16_kernel<<<1024, 256, 0, stream>>>(w_hh_f0, wh_f0, 262144);
  cast_f16_kernel<<<1024, 256, 0, stream>>>(w_hh_r0, wh_r0, 262144);
  cast_f16_kernel<<<1024, 256, 0, stream>>>(w_hh_f1, wh_f1, 262144);
  cast_f16_kernel<<<1024, 256, 0, stream>>>(w_hh_r1, wh_r1, 262144);

  conv_bn_kernel<<<M_, 256, 0, stream>>>(x, conv_w, conv_b, bn_g, bn_bb, bn_m, bn_v, ybf);

  proj_gemm_kernel<<<dim3(512, 16, 2), 256, 0, stream>>>(
      ybf, wb_f0, wb_r0, b_f0, b_r0, pre_f, pre_r, 256);

  scan2_kernel<<<64, 1024, SCAN_LDS, stream>>>(
      pre_f, pre_r, (const u32*)wh_f0, (const u32*)wh_r0, (void*)h0cat, 1);

  proj_gemm_kernel<<<dim3(512, 16, 2), 256, 0, stream>>>(
      h0cat, wb_f1, wb_r1, b_f1, b_r1, pre_f, pre_r, 512);

  scan2_kernel<<<64, 1024, SCAN_LDS, stream>>>(
      pre_f, pre_r, (const u32*)wh_f1, (const u32*)wh_r1, (void*)h1cat, 0);

  fc_init_kernel<<<24, 256, 0, stream>>>(fc1_b, fc2_b, out);
  fc_kernel<<<256, 256, 0, stream>>>(h1cat, fc1_w, fc2_w, out);
}

// Round 3
// 4852.374 us; speedup vs baseline: 6.8290x; 1.1382x over previous
//
#include <hip/hip_runtime.h>
#include <hip/hip_fp16.h>

typedef unsigned short u16;
typedef unsigned int   u32;

#define B_   32
#define T_   2048
#define C_   256
#define H_   256
#define TC_  1024
#define M_   (B_*TC_)   // 32768

using bf16x8 = __attribute__((ext_vector_type(8))) short;
using f32x4  = __attribute__((ext_vector_type(4))) float;
typedef _Float16 f16x2 __attribute__((ext_vector_type(2)));

__device__ __forceinline__ u16 f2bf(float f) {
  u32 u = __float_as_uint(f);
  u32 r = u + 0x7fffu + ((u >> 16) & 1u);
  return (u16)(r >> 16);
}
__device__ __forceinline__ float sigmf(float x) { return 1.f / (1.f + __expf(-x)); }
// tanh(x) = 1 - 2/(e^{2x}+1); exact limits at +-inf, ~1e-7 rel error
__device__ __forceinline__ float tanhfast(float x) {
  float e = __expf(2.f * x);
  return 1.f - 2.f / (e + 1.f);
}
__device__ __forceinline__ float dot2(u32 w, u32 h, float acc) {
  return __builtin_amdgcn_fdot2(__builtin_bit_cast(f16x2, w),
                                __builtin_bit_cast(f16x2, h), acc, false);
}

// ---------------- casts ----------------
__global__ void cast_bf16_kernel(const float* __restrict__ src, u16* __restrict__ dst, int n) {
  int i = blockIdx.x * 256 + threadIdx.x;
  if (i < n) dst[i] = f2bf(src[i]);
}
__global__ void cast_f16_kernel(const float* __restrict__ src, u16* __restrict__ dst, int n) {
  int i = blockIdx.x * 256 + threadIdx.x;
  if (i < n) dst[i] = __half_as_ushort(__float2half(src[i]));
}

// ---------------- conv + bn + relu -> y bf16 (B*TC, C) ----------------
__global__ __launch_bounds__(256)
void conv_bn_kernel(const float* __restrict__ x, const float* __restrict__ cw,
                    const float* __restrict__ cb, const float* __restrict__ bng,
                    const float* __restrict__ bnb, const float* __restrict__ bnm,
                    const float* __restrict__ bnv, u16* __restrict__ ybf) {
  int c = threadIdx.x;
  int bt = blockIdx.x;                  // b*TC + t
  int t = bt & (TC_ - 1), b = bt >> 10;
  const float* xr = x + (size_t)b * T_;
  float xm1 = (t > 0) ? xr[2 * t - 1] : 0.f;
  float x0 = xr[2 * t], xp1 = xr[2 * t + 1];
  float w0 = cw[c * 3], w1 = cw[c * 3 + 1], w2 = cw[c * 3 + 2];
  float inv = bng[c] * rsqrtf(bnv[c] + 1e-5f);
  float beta = bnb[c] - bnm[c] * inv;
  float v = w0 * xm1 + w1 * x0 + w2 * xp1 + cb[c];
  v = v * inv + beta;
  v = fmaxf(v, 0.f);
  ybf[(size_t)bt * C_ + c] = f2bf(v);
}

// ---------------- projection GEMM v2: LDS-staged 128x128 tile ----------------
// pre = A(bf16 MxK) @ W(bf16 1024xK)^T + bias. 256 thr = 4 waves, each wave a
// 64x64 quadrant as 4x4 MFMA 16x16x32 tiles. BK=32. Row pad +8 u16 (16B) keeps
// b128 alignment; stride 80B -> worst 2-way bank aliasing (free).
#define PBK 32
#define APAD 8
__global__ __launch_bounds__(256)
void proj_gemm2_kernel(const u16* __restrict__ A,
                       const u16* __restrict__ Wf, const u16* __restrict__ Wr,
                       const float* __restrict__ bf, const float* __restrict__ br,
                       float* __restrict__ outf, float* __restrict__ outr,
                       int K) {
  const u16* W = blockIdx.z ? Wr : Wf;
  const float* bias = blockIdx.z ? br : bf;
  float* out = blockIdx.z ? outr : outf;
  __shared__ u16 As[128][PBK + APAD];
  __shared__ u16 Ws[128][PBK + APAD];
  const int tid = threadIdx.x;
  const int wave = tid >> 6, lane = tid & 63;
  const int l16 = lane & 15, quad = lane >> 4;
  const int m0 = blockIdx.x * 128, n0 = blockIdx.y * 128;
  const int wm = (wave >> 1) * 64, wn = (wave & 1) * 64;
  const int srow = tid >> 2, scol = (tid & 3) * 8;
  const u16* Ag0 = A + (size_t)(m0 + srow) * K + scol;
  const u16* Ag1 = Ag0 + (size_t)64 * K;
  const u16* Wg0 = W + (size_t)(n0 + srow) * K + scol;
  const u16* Wg1 = Wg0 + (size_t)64 * K;
  f32x4 acc[4][4] = {};
  for (int k0 = 0; k0 < K; k0 += PBK) {
    *(uint4*)&As[srow][scol]      = *(const uint4*)(Ag0 + k0);
    *(uint4*)&As[srow + 64][scol] = *(const uint4*)(Ag1 + k0);
    *(uint4*)&Ws[srow][scol]      = *(const uint4*)(Wg0 + k0);
    *(uint4*)&Ws[srow + 64][scol] = *(const uint4*)(Wg1 + k0);
    __syncthreads();
    bf16x8 af[4], wf[4];
#pragma unroll
    for (int i = 0; i < 4; ++i) {
      af[i] = *(const bf16x8*)&As[wm + 16 * i + l16][quad * 8];
      wf[i] = *(const bf16x8*)&Ws[wn + 16 * i + l16][quad * 8];
    }
#pragma unroll
    for (int i = 0; i < 4; ++i)
#pragma unroll
      for (int j = 0; j < 4; ++j)
        acc[i][j] = __builtin_amdgcn_mfma_f32_16x16x32_bf16(af[i], wf[j], acc[i][j], 0, 0, 0);
    __syncthreads();
  }
  float bv[4];
#pragma unroll
  for (int j = 0; j < 4; ++j) bv[j] = bias[n0 + wn + 16 * j + l16];
#pragma unroll
  for (int i = 0; i < 4; ++i) {
    int row = m0 + wm + 16 * i + quad * 4;
#pragma unroll
    for (int j = 0; j < 4; ++j) {
      int col = n0 + wn + 16 * j + l16;
#pragma unroll
      for (int r = 0; r < 4; ++r)
        out[(size_t)(row + r) * 1024 + col] = acc[i][j][r] + bv[j];
    }
  }
}

// ---------------- LSTM scan v3: 1 WG/chain, 3-phase step, cheap tanh ----------------
// 1024 threads. tid = p + 512*kh: thread owns gate rows {p, p+512}, k-half kh.
// Weights/thread: 96 half2 in VGPRs + 32 in LDS (128 KB). h packed f16 in LDS.
// Step: dot(1024t) -> bar -> activate gates(1024t, 1 transcendental each) ->
// bar -> c/h update(256t, 1 cheap tanh) -> bar.
#define SCAN_LDS (131072 + 512 + 8192)   // wlds + hbuf + gpart = 139776 B
__global__ __launch_bounds__(1024, 1)
void scan3_kernel(const float* __restrict__ pre_f, const float* __restrict__ pre_r,
                  const u32* __restrict__ whh_f, const u32* __restrict__ whh_r,
                  void* __restrict__ outp, int out_bf16) {
  extern __shared__ char smem[];
  u32*   wlds  = (u32*)smem;                       // [8][1024][4] u32
  u32*   hbuf  = (u32*)(smem + 131072);            // [128] packed f16 pairs
  float* gpart = (float*)(smem + 131072 + 512);    // [2][1024]
  const int tid = threadIdx.x;
  const int p = tid & 511, kh = tid >> 9;
  const int chain = blockIdx.x;
  const int dir = chain & 1, b = chain >> 1;
  const float* pre = dir ? pre_r : pre_f;
  const u32* whh = dir ? whh_r : whh_f;            // f16-pair packed [1024][128]

  u32 wreg0[48], wreg1[48];
  {
    const u32* w0p = whh + (size_t)p * 128 + kh * 64;
    const u32* w1p = w0p + (size_t)512 * 128;
#pragma unroll
    for (int c = 0; c < 12; ++c) {
      uint4 a = *(const uint4*)(w0p + c * 4);
      wreg0[c*4+0] = a.x; wreg0[c*4+1] = a.y; wreg0[c*4+2] = a.z; wreg0[c*4+3] = a.w;
      uint4 bq = *(const uint4*)(w1p + c * 4);
      wreg1[c*4+0] = bq.x; wreg1[c*4+1] = bq.y; wreg1[c*4+2] = bq.z; wreg1[c*4+3] = bq.w;
    }
#pragma unroll
    for (int c = 0; c < 4; ++c) {
      *(uint4*)(wlds + ((size_t)c * 1024 + tid) * 4)       = *(const uint4*)(w0p + (12 + c) * 4);
      *(uint4*)(wlds + ((size_t)(4 + c) * 1024 + tid) * 4) = *(const uint4*)(w1p + (12 + c) * 4);
    }
  }
  if (tid < 128) hbuf[tid] = 0u;
  float cst = 0.f;
  __syncthreads();

  const u32* hb = hbuf + kh * 64;
  // preload pre for t=0
  float cur0 = 0.f, cur1 = 0.f;
  if (kh == 0) {
    const float* pr = pre + ((size_t)b * TC_ + (dir ? TC_ - 1 : 0)) * 1024;
    cur0 = pr[p]; cur1 = pr[p + 512];
  }
  for (int t = 0; t < TC_; ++t) {
    const int tt = dir ? (TC_ - 1 - t) : t;
    // prefetch next step's pre
    float nxt0 = 0.f, nxt1 = 0.f;
    if (kh == 0 && t + 1 < TC_) {
      const int tn = dir ? (TC_ - 2 - t) : (t + 1);
      const float* pr = pre + ((size_t)b * TC_ + tn) * 1024;
      nxt0 = pr[p]; nxt1 = pr[p + 512];
    }
    float acc0 = 0.f, acc1 = 0.f;
#pragma unroll
    for (int c = 0; c < 12; ++c) {
      uint4 h4 = *(const uint4*)(hb + c * 4);
      acc0 = dot2(wreg0[c*4+0], h4.x, acc0);
      acc0 = dot2(wreg0[c*4+1], h4.y, acc0);
      acc0 = dot2(wreg0[c*4+2], h4.z, acc0);
      acc0 = dot2(wreg0[c*4+3], h4.w, acc0);
      acc1 = dot2(wreg1[c*4+0], h4.x, acc1);
      acc1 = dot2(wreg1[c*4+1], h4.y, acc1);
      acc1 = dot2(wreg1[c*4+2], h4.z, acc1);
      acc1 = dot2(wreg1[c*4+3], h4.w, acc1);
    }
#pragma unroll
    for (int c = 0; c < 4; ++c) {
      uint4 h4 = *(const uint4*)(hb + (12 + c) * 4);
      uint4 w0 = *(const uint4*)(wlds + ((size_t)c * 1024 + tid) * 4);
      uint4 w1 = *(const uint4*)(wlds + ((size_t)(4 + c) * 1024 + tid) * 4);
      acc0 = dot2(w0.x, h4.x, acc0);
      acc0 = dot2(w0.y, h4.y, acc0);
      acc0 = dot2(w0.z, h4.z, acc0);
      acc0 = dot2(w0.w, h4.w, acc0);
      acc1 = dot2(w1.x, h4.x, acc1);
      acc1 = dot2(w1.y, h4.y, acc1);
      acc1 = dot2(w1.z, h4.z, acc1);
      acc1 = dot2(w1.w, h4.w, acc1);
    }
    if (kh == 0) { acc0 += cur0; acc1 += cur1; }
    gpart[kh * 1024 + p]       = acc0;
    gpart[kh * 1024 + p + 512] = acc1;
    __syncthreads();
    // phase B: activate all 1024 gates, one per thread (wave-uniform branch)
    {
      float g = gpart[tid] + gpart[1024 + tid];
      float a = ((tid >> 8) == 2) ? tanhfast(g) : sigmf(g);
      gpart[tid] = a;     // only thread tid touches gpart[tid] in this phase
    }
    __syncthreads();
    // phase C: elementwise state update on 256 threads
    if (tid < 256) {
      const int j = tid;
      float i_ = gpart[j], f_ = gpart[256 + j], g_ = gpart[512 + j], o_ = gpart[768 + j];
      cst = f_ * cst + i_ * g_;
      float h = o_ * tanhfast(cst);
      size_t oi = ((size_t)b * TC_ + tt) * 512 + (size_t)dir * 256 + j;
      if (out_bf16) ((u16*)outp)[oi] = f2bf(h);
      else          ((float*)outp)[oi] = h;
      u16 hu = __half_as_ushort(__float2half(h));
      u16 hn = (u16)__shfl_down((int)hu, 1);
      if ((j & 1) == 0) hbuf[j >> 1] = (u32)hu | ((u32)hn << 16);
    }
    cur0 = nxt0; cur1 = nxt1;
    __syncthreads();
  }
}

// ---------------- FC heads ----------------
__global__ void fc_init_kernel(const float* __restrict__ fc1_b, const float* __restrict__ fc2_b,
                               float* __restrict__ out) {
  int i = blockIdx.x * 256 + threadIdx.x;
  if (i < 3200) out[i] = fc1_b[i % 100];
  else if (i < 6080) out[i] = fc2_b[(i - 3200) % 90];
}

#define FCK 1024
#define FCSUB 64
__global__ __launch_bounds__(256)
void fc_kernel(const float* __restrict__ flat, const float* __restrict__ w1,
               const float* __restrict__ w2, float* __restrict__ out) {
  __shared__ float fs[32][FCSUB + 1];
  __shared__ float ws[192][FCSUB + 1];
  int tid = threadIdx.x;
  int tn = tid & 31, tb = tid >> 5;
  size_t k0 = (size_t)blockIdx.x * FCK;
  float acc[4][6] = {};
  for (int kc = 0; kc < FCK; kc += FCSUB) {
    __syncthreads();
    for (int idx = tid; idx < 32 * FCSUB; idx += 256) {
      int bb = idx >> 6, j = idx & 63;
      fs[bb][j] = flat[(size_t)bb * 524288 + k0 + kc + j];
    }
    for (int idx = tid; idx < 192 * FCSUB; idx += 256) {
      int n = idx >> 6, j = idx & 63;
      float v = 0.f;
      if (n < 100)      v = w1[(size_t)n * 524288 + k0 + kc + j];
      else if (n < 190) v = w2[(size_t)(n - 100) * 524288 + k0 + kc + j];
      ws[n][j] = v;
    }
    __syncthreads();
    for (int j = 0; j < FCSUB; ++j) {
      float fv[4], wv[6];
#pragma unroll
      for (int m = 0; m < 4; ++m) fv[m] = fs[tb + 8 * m][j];
#pragma unroll
      for (int mm = 0; mm < 6; ++mm) wv[mm] = ws[tn + 32 * mm][j];
#pragma unroll
      for (int m = 0; m < 4; ++m)
#pragma unroll
        for (int mm = 0; mm < 6; ++mm) acc[m][mm] = fmaf(fv[m], wv[mm], acc[m][mm]);
    }
  }
#pragma unroll
  for (int m = 0; m < 4; ++m)
#pragma unroll
    for (int mm = 0; mm < 6; ++mm) {
      int n = tn + 32 * mm, bb = tb + 8 * m;
      if (n < 190) {
        int oi = (n < 100) ? (bb * 100 + n) : (3200 + bb * 90 + (n - 100));
        atomicAdd(out + oi, acc[m][mm]);
      }
    }
}

// ---------------- launcher ----------------
extern "C" void kernel_launch(void* const* d_in, const int* in_sizes, int n_in,
                              void* d_out, int out_size, void* d_ws, size_t ws_size,
                              hipStream_t stream) {
  const float* x       = (const float*)d_in[0];
  const float* conv_w  = (const float*)d_in[1];
  const float* conv_b  = (const float*)d_in[2];
  const float* bn_g    = (const float*)d_in[3];
  const float* bn_bb   = (const float*)d_in[4];
  const float* bn_m    = (const float*)d_in[5];
  const float* bn_v    = (const float*)d_in[6];
  const float* w_ih_f0 = (const float*)d_in[7];
  const float* w_hh_f0 = (const float*)d_in[8];
  const float* b_f0    = (const float*)d_in[9];
  const float* w_ih_r0 = (const float*)d_in[10];
  const float* w_hh_r0 = (const float*)d_in[11];
  const float* b_r0    = (const float*)d_in[12];
  const float* w_ih_f1 = (const float*)d_in[13];
  const float* w_hh_f1 = (const float*)d_in[14];
  const float* b_f1    = (const float*)d_in[15];
  const float* w_ih_r1 = (const float*)d_in[16];
  const float* w_hh_r1 = (const float*)d_in[17];
  const float* b_r1    = (const float*)d_in[18];
  const float* fc1_w   = (const float*)d_in[19];
  const float* fc1_b   = (const float*)d_in[20];
  const float* fc2_w   = (const float*)d_in[21];
  const float* fc2_b   = (const float*)d_in[22];
  float* out = (float*)d_out;

  char* base = (char*)d_ws;
  size_t off = 0;
  auto carve = [&](size_t bytes) -> char* {
    char* p = base + off;
    off += (bytes + 511) & ~(size_t)511;
    return p;
  };
  u16*   ybf   = (u16*)carve((size_t)M_ * 256 * 2);
  u16*   wb_f0 = (u16*)carve((size_t)262144 * 2);
  u16*   wb_r0 = (u16*)carve((size_t)262144 * 2);
  u16*   wb_f1 = (u16*)carve((size_t)524288 * 2);
  u16*   wb_r1 = (u16*)carve((size_t)524288 * 2);
  u16*   wh_f0 = (u16*)carve((size_t)262144 * 2);
  u16*   wh_r0 = (u16*)carve((size_t)262144 * 2);
  u16*   wh_f1 = (u16*)carve((size_t)262144 * 2);
  u16*   wh_r1 = (u16*)carve((size_t)262144 * 2);
  u16*   h0cat = (u16*)carve((size_t)M_ * 512 * 2);
  float* h1cat = (float*)carve((size_t)M_ * 512 * 4);
  float* pre_f = (float*)carve((size_t)M_ * 1024 * 4);
  float* pre_r = (float*)carve((size_t)M_ * 1024 * 4);
  if (off > ws_size) return;

  hipFuncSetAttribute((const void*)scan3_kernel,
                      hipFuncAttributeMaxDynamicSharedMemorySize, SCAN_LDS);

  cast_bf16_kernel<<<1024, 256, 0, stream>>>(w_ih_f0, wb_f0, 262144);
  cast_bf16_kernel<<<1024, 256, 0, stream>>>(w_ih_r0, wb_r0, 262144);
  cast_bf16_kernel<<<2048, 256, 0, stream>>>(w_ih_f1, wb_f1, 524288);
  cast_bf16_kernel<<<2048, 256, 0, stream>>>(w_ih_r1, wb_r1, 524288);
  cast_f16_kernel<<<1024, 256, 0, stream>>>(w_hh_f0, wh_f0, 262144);
  cast_f16_kernel<<<1024, 256, 0, stream>>>(w_hh_r0, wh_r0, 262144);
  cast_f16_kernel<<<1024, 256, 0, stream>>>(w_hh_f1, wh_f1, 262144);
  cast_f16_kernel<<<1024, 256, 0, stream>>>(w_hh_r1, wh_r1, 262144);

  conv_bn_kernel<<<M_, 256, 0, stream>>>(x, conv_w, conv_b, bn_g, bn_bb, bn_m, bn_v, ybf);

  proj_gemm2_kernel<<<dim3(256, 8, 2), 256, 0, stream>>>(
      ybf, wb_f0, wb_r0, b_f0, b_r0, pre_f, pre_r, 256);

  scan3_kernel<<<64, 1024, SCAN_LDS, stream>>>(
      pre_f, pre_r, (const u32*)wh_f0, (const u32*)wh_r0, (void*)h0cat, 1);

  proj_gemm2_kernel<<<dim3(256, 8, 2), 256, 0, stream>>>(
      h0cat, wb_f1, wb_r1, b_f1, b_r1, pre_f, pre_r, 512);

  scan3_kernel<<<64, 1024, SCAN_LDS, stream>>>(
      pre_f, pre_r, (const u32*)wh_f1, (const u32*)wh_r1, (void*)h1cat, 0);

  fc_init_kernel<<<24, 256, 0, stream>>>(fc1_b, fc2_b, out);
  fc_kernel<<<512, 256, 0, stream>>>(h1cat, fc1_w, fc2_w, out);
}